// Round 6
// baseline (887.974 us; speedup 1.0000x reference)
//
#include <hip/hip_runtime.h>
#include <hip/hip_fp16.h>

#define NPIX 65536
#define WIMG 256
#define HIMG 256
#define TW 16
#define TH 8
#define HSTR 24      // halo row stride (halves): 10 rows x 24, 18 used per row
#define NSLOT 240

typedef __attribute__((ext_vector_type(8))) _Float16 half8;
typedef __attribute__((ext_vector_type(4))) float f32x4;

__device__ __forceinline__ unsigned int h2u(__half2 h) {
  union { __half2 h; unsigned int u; } c; c.h = h; return c.u;
}
// qs/ks layout: [ch][px 0..127] swizzled; pxblk = px>>3
__device__ __forceinline__ int qk_idx(int ch, int pxblk) {
  return ch * 128 + ((pxblk ^ (ch & 7)) << 3);
}
__device__ __forceinline__ void ld16_lds(const void* g, void* l) {
  __builtin_amdgcn_global_load_lds(
      (const __attribute__((address_space(1))) unsigned int*)g,
      (__attribute__((address_space(3))) unsigned int*)l, 16, 0, 0);
}
__device__ __forceinline__ half8 splat8(_Float16 s) {
  half8 r = {s, s, s, s, s, s, s, s};
  return r;
}

__global__ void k_zero(float* __restrict__ p, int n) {
  int i = blockIdx.x * 256 + threadIdx.x;
  if (i < n) p[i] = 0.0f;
}

// x f32 [b][128c][px] -> xT fp16 [b*2+br][px][c64]
__global__ __launch_bounds__(256)
void k_xt(const float* __restrict__ x, __half* __restrict__ xT) {
  __shared__ _Float16 tile[64 * 257];
  const int strip = blockIdx.x;
  const int br = blockIdx.y, b = blockIdx.z;
  const int tid = threadIdx.x;
  const float* xb = x + ((size_t)b * 128 + br * 64) * NPIX + strip * 256;
  #pragma unroll 8
  for (int c = 0; c < 64; ++c)
    tile[c * 257 + tid] = (_Float16)xb[(size_t)c * NPIX + tid];
  __syncthreads();
  __half* xo = xT + ((size_t)(b * 2 + br) * NPIX + strip * 256) * 64;
  const int j = tid & 7;
  #pragma unroll
  for (int i = 0; i < 8; ++i) {
    int p = (tid >> 3) + i * 32;
    half8 h;
    #pragma unroll
    for (int k = 0; k < 8; ++k) h[k] = tile[(j * 8 + k) * 257 + p];
    *(half8*)((_Float16*)xo + p * 64 + j * 8) = h;
  }
}

// Fused: DMA-stage x halo -> (pw*dw) folded GEMM (K=576) via MFMA -> {v global, q/k LDS}
// -> gram (qk, qq, kk) via MFMA -> atomics.  2 barriers total.
__global__ __launch_bounds__(256, 2)
void k_qkv(const __half* __restrict__ xT,
           const float* __restrict__ wqkv1, const float* __restrict__ wqkv2,
           const float* __restrict__ wdw1, const float* __restrict__ wdw2,
           const float* __restrict__ zpage,
           __half* __restrict__ vbuf, float* __restrict__ gram,
           float* __restrict__ sqq, float* __restrict__ sqk)
{
  __shared__ __align__(16) _Float16 xs[NSLOT * 64];   // 30720 B [slot][c] chunk-swizzled
  __shared__ __align__(16) _Float16 qs[64 * 128];     // 16384 B
  __shared__ __align__(16) _Float16 ks[64 * 128];     // 16384 B

  const int tid = threadIdx.x;
  const int lane = tid & 63;
  const int wid = tid >> 6;
  const int tile = blockIdx.x;
  const int br = blockIdx.y;
  const int b = blockIdx.z;
  const int tx0 = (tile & 15) * TW;
  const int ty0 = (tile >> 4) * TH;

  const float* wqkv = br ? wqkv2 : wqkv1;
  const float* wdw  = br ? wdw2 : wdw1;
  const __half* xTimg = xT + (size_t)(b * 2 + br) * NPIX * 64;

  // ---- async DMA staging: 30 x 1KB, source-swizzled, LDS linear ----
  {
    const int j = lane & 7, pl = lane >> 3;
    for (int it = wid; it < 30; it += 4) {
      int s = it * 8;
      int slot = s + pl;
      int hy = slot / HSTR;
      int hx = slot - hy * HSTR;
      int gy = ty0 - 1 + hy, gx = tx0 - 1 + hx;
      bool valid = (hx < 18) && ((unsigned)gy < HIMG) && ((unsigned)gx < WIMG);
      const void* src = valid
        ? (const void*)((const _Float16*)xTimg + (size_t)(gy * WIMG + gx) * 64
                        + ((j ^ (slot & 7)) << 3))
        : (const void*)((const char*)zpage + lane * 16);
      ld16_lds(src, (void*)(xs + s * 64));
    }
  }
  asm volatile("s_waitcnt vmcnt(0)" ::: "memory");
  __syncthreads();

  const int col = lane & 15;
  const int qrow = lane >> 4;          // 0..3

  // parts: p=0 -> v (w part 2), p=1 -> q (w part 0), p=2 -> k (w part 1)
  for (int p = 0; p < 3; ++p) {
    const int pw = (p == 0) ? 2 : (p - 1);

    // pointwise weight B-fragments (f16) into registers
    half8 wf[2][4];
    #pragma unroll
    for (int nt = 0; nt < 4; ++nt)
      #pragma unroll
      for (int kc = 0; kc < 2; ++kc) {
        const float* wr = wqkv + (size_t)(pw * 64 + nt * 16 + col) * 64
                                 + kc * 32 + qrow * 8;
        float4 wa = *(const float4*)wr;
        float4 wb4 = *(const float4*)(wr + 4);
        half8 h;
        h[0] = (_Float16)wa.x;  h[1] = (_Float16)wa.y;
        h[2] = (_Float16)wa.z;  h[3] = (_Float16)wa.w;
        h[4] = (_Float16)wb4.x; h[5] = (_Float16)wb4.y;
        h[6] = (_Float16)wb4.z; h[7] = (_Float16)wb4.w;
        wf[kc][nt] = h;
      }
    // depthwise scalars (per-lane o = nt*16+col)
    _Float16 wdwh[4][9];
    #pragma unroll
    for (int nt = 0; nt < 4; ++nt) {
      const float* wr = wdw + (size_t)(pw * 64 + nt * 16 + col) * 9;
      #pragma unroll
      for (int t = 0; t < 9; ++t) wdwh[nt][t] = (_Float16)wr[t];
    }

    // 2 m-tiles (image rows) per wave; K = 9 taps x 64 c folded
    #pragma unroll
    for (int mi = 0; mi < 2; ++mi) {
      const int py = wid * 2 + mi;
      f32x4 acc[4] = {{0,0,0,0},{0,0,0,0},{0,0,0,0},{0,0,0,0}};
      #pragma unroll
      for (int kc = 0; kc < 2; ++kc) {
        half8 A[9];
        #pragma unroll
        for (int t = 0; t < 9; ++t) {
          int slot = (py + t / 3) * HSTR + col + (t % 3);   // (py+1+dy-1)... dy=t/3-1
          A[t] = *(const half8*)(xs + slot * 64 +
                                 (((kc * 4 + qrow) ^ (slot & 7)) << 3));
        }
        #pragma unroll
        for (int t = 0; t < 9; ++t)
          #pragma unroll
          for (int nt = 0; nt < 4; ++nt) {
            half8 Bf = wf[kc][nt] * splat8(wdwh[nt][t]);
            acc[nt] = __builtin_amdgcn_mfma_f32_16x16x32_f16(A[t], Bf, acc[nt], 0, 0, 0);
          }
      }
      // store: lane holds cols qrow*4..+3 of row py, o = nt*16+col
      if (p == 0) {
        #pragma unroll
        for (int nt = 0; nt < 4; ++nt) {
          __half* vrow = (__half*)(vbuf
              + ((size_t)((br * 4 + b) * 64 + nt * 16 + col)) * NPIX
              + (ty0 + py) * WIMG + tx0 + qrow * 4);
          uint2 s2 = {h2u(__floats2half2_rn(acc[nt][0], acc[nt][1])),
                      h2u(__floats2half2_rn(acc[nt][2], acc[nt][3]))};
          *(uint2*)vrow = s2;
        }
      } else {
        _Float16* dst = (p == 1) ? qs : ks;
        int px = py * 16 + qrow * 4;
        #pragma unroll
        for (int nt = 0; nt < 4; ++nt) {
          int ch = nt * 16 + col;
          uint2 s2 = {h2u(__floats2half2_rn(acc[nt][0], acc[nt][1])),
                      h2u(__floats2half2_rn(acc[nt][2], acc[nt][3]))};
          *(uint2*)(dst + qk_idx(ch, px >> 3) + (px & 4)) = s2;
        }
      }
    }
  }
  __syncthreads();

  // ---- gram: qk + qq + kk diag head-tiles via MFMA, K=128 px ----
  {
    f32x4 gqk = {0,0,0,0}, gqq = {0,0,0,0}, gkk = {0,0,0,0};
    int ch = wid * 16 + col;
    #pragma unroll
    for (int kc = 0; kc < 4; ++kc) {
      int pb = kc * 4 + qrow;
      half8 aq = *(const half8*)(qs + qk_idx(ch, pb));
      half8 bk = *(const half8*)(ks + qk_idx(ch, pb));
      gqk = __builtin_amdgcn_mfma_f32_16x16x32_f16(aq, bk, gqk, 0, 0, 0);
      gqq = __builtin_amdgcn_mfma_f32_16x16x32_f16(aq, aq, gqq, 0, 0, 0);
      gkk = __builtin_amdgcn_mfma_f32_16x16x32_f16(bk, bk, gkk, 0, 0, 0);
    }
    const int gb_off = (br * 4 + b);
    if (((lane >> 3) & 1) == (lane >> 5)) {
      float* gb = gram + gb_off * 512;
      int kch = ch;
      int qc0 = wid * 16 + qrow * 4;
      #pragma unroll
      for (int r = 0; r < 4; ++r) {
        int qch = qc0 + r;
        atomicAdd(&gb[(qch >> 3) * 64 + (qch & 7) * 8 + (kch & 7)], gqk[r]);
      }
    }
    if ((col >> 2) == qrow) {   // diagonal lanes
      atomicAdd(&sqq[gb_off * 64 + ch], gqq[lane & 3]);
      atomicAdd(&sqk[gb_off * 64 + ch], gkk[lane & 3]);
    }
  }
}

// softmax(G scaled) -> attn, Weff = w_po @ blockdiag(attn), stored transposed [c'][o]
__global__ __launch_bounds__(64)
void k_attn(const float* __restrict__ gram, const float* __restrict__ sqq,
            const float* __restrict__ sqk,
            const float* __restrict__ wpo1, const float* __restrict__ wpo2,
            const float* __restrict__ t1, const float* __restrict__ t2,
            float* __restrict__ weff)
{
  const int br = blockIdx.x, b = blockIdx.y;
  const int t = threadIdx.x;
  __shared__ float attn[8][8][8];
  const float* gb = gram + (br * 4 + b) * 512;
  const float* sq = sqq + (br * 4 + b) * 64;
  const float* sk = sqk + (br * 4 + b) * 64;
  const float* tt = br ? t2 : t1;
  {
    int h = t >> 3, cq = t & 7;
    float ts = tt[h];
    float qn = fmaxf(sqrtf(sq[h * 8 + cq]), 1e-12f);
    float lg[8], m = -1e30f;
    #pragma unroll
    for (int d2 = 0; d2 < 8; ++d2) {
      float kn = fmaxf(sqrtf(sk[h * 8 + d2]), 1e-12f);
      lg[d2] = ts * gb[h * 64 + cq * 8 + d2] / (qn * kn);
      m = fmaxf(m, lg[d2]);
    }
    float s = 0.f;
    #pragma unroll
    for (int d2 = 0; d2 < 8; ++d2) { lg[d2] = expf(lg[d2] - m); s += lg[d2]; }
    float inv = 1.0f / s;
    #pragma unroll
    for (int d2 = 0; d2 < 8; ++d2) attn[h][cq][d2] = lg[d2] * inv;
  }
  __syncthreads();
  const float* wpo = br ? wpo2 : wpo1;
  float* wb = weff + (br * 4 + b) * 4096;
  for (int cp = 0; cp < 64; ++cp) {
    int hp = cp >> 3, ip = cp & 7;
    float acc = 0.f;
    #pragma unroll
    for (int j = 0; j < 8; ++j)
      acc += wpo[t * 64 + hp * 8 + j] * attn[hp][j][ip];
    wb[cp * 64 + t] = acc;   // [c'][o]
  }
}

// out[b, obr*64+o, px] = sum_c Weff[obr][b][c][o] * v[1-obr][b][c][px]
__global__ __launch_bounds__(256)
void k_out(const __half* __restrict__ vbuf, const float* __restrict__ weff,
           float* __restrict__ out)
{
  const int obr = blockIdx.y, b = blockIdx.z;
  const int px = blockIdx.x * 256 + threadIdx.x;
  const float* wb = weff + (obr * 4 + b) * 4096;   // [c][o]
  const __half* vp = vbuf + ((size_t)((1 - obr) * 4 + b) * 64) * NPIX + px;
  float acc[64];
  #pragma unroll
  for (int o = 0; o < 64; ++o) acc[o] = 0.0f;
  for (int c = 0; c < 64; ++c) {
    float vc = __half2float(vp[(size_t)c * NPIX]);
    const float* wr = wb + c * 64;   // block-uniform -> s_load
    #pragma unroll
    for (int o = 0; o < 64; ++o) acc[o] = fmaf(wr[o], vc, acc[o]);
  }
  float* op = out + ((size_t)b * 128 + obr * 64) * NPIX + px;
  #pragma unroll
  for (int o = 0; o < 64; ++o) op[(size_t)o * NPIX] = acc[o];
}

extern "C" void kernel_launch(void* const* d_in, const int* in_sizes, int n_in,
                              void* d_out, int out_size, void* d_ws, size_t ws_size,
                              hipStream_t stream) {
  const float* x     = (const float*)d_in[0];
  const float* wqkv1 = (const float*)d_in[1];
  const float* wqkv2 = (const float*)d_in[2];
  const float* wdw1  = (const float*)d_in[3];
  const float* wdw2  = (const float*)d_in[4];
  const float* wpo1  = (const float*)d_in[5];
  const float* wpo2  = (const float*)d_in[6];
  const float* t1    = (const float*)d_in[7];
  const float* t2    = (const float*)d_in[8];

  char* ws = (char*)d_ws;
  __half* vbuf = (__half*)ws;                     // 67,108,864 B
  float* gram  = (float*)(ws + 67108864);         // 4096 f32
  float* sqq   = gram + 4096;                     // 512
  float* sqk   = sqq + 512;                       // 512
  float* zpage = sqk + 512;                       // 1024 f32 (zeros for OOB DMA)
  float* weff  = zpage + 1024;                    // 32768 f32

  __half* xT = (__half*)d_out;   // xT in not-yet-written d_out

  k_zero<<<dim3(24), dim3(256), 0, stream>>>(gram, 6144);
  k_xt<<<dim3(256, 2, 4), dim3(256), 0, stream>>>(x, xT);
  k_qkv<<<dim3(512, 2, 4), dim3(256), 0, stream>>>(xT, wqkv1, wqkv2, wdw1, wdw2,
                                                   zpage, vbuf, gram, sqq, sqk);
  k_attn<<<dim3(2, 4), dim3(64), 0, stream>>>(gram, sqq, sqk, wpo1, wpo2, t1, t2, weff);
  k_out<<<dim3(256, 2, 4), dim3(256), 0, stream>>>(vbuf, weff, (float*)d_out);
}